// Round 6
// baseline (651.389 us; speedup 1.0000x reference)
//
#include <hip/hip_runtime.h>

typedef short s16x8 __attribute__((ext_vector_type(8)));
typedef float f32x4 __attribute__((ext_vector_type(4)));

#define B_   128
#define A_   64
#define N_   2000
#define DIN  128
#define HID  512
#define H_   8
#define HD_  64
#define ND_  16
#define NT_  32

__device__ __forceinline__ unsigned short f2bf(float f) {
  union { float f; unsigned int u; } v; v.f = f;
  unsigned int u = v.u;
  unsigned int r = (u + 0x7fffu + ((u >> 16) & 1u)) >> 16;
  return (unsigned short)r;
}

__device__ __forceinline__ float bf2f(unsigned int u16v) {
  union { unsigned int u; float f; } v; v.u = u16v << 16;
  return v.f;
}

__device__ __forceinline__ f32x4 mfma16(s16x8 a, s16x8 b, f32x4 c) {
  return __builtin_amdgcn_mfma_f32_16x16x32_bf16(a, b, c, 0, 0, 0);
}

__device__ __forceinline__ unsigned int cvtpk(float lo, float hi) {
  unsigned int r;
  asm("v_cvt_pk_bf16_f32 %0, %1, %2" : "=&v"(r) : "v"(lo), "v"(hi));
  return r;
}

__device__ __forceinline__ void gload16(const void* g, void* l) {
  __builtin_amdgcn_global_load_lds(
      (const __attribute__((address_space(1))) unsigned int*)g,
      (__attribute__((address_space(3))) unsigned int*)l, 16, 0, 0);
}

__device__ __forceinline__ void barrier_full() {
  asm volatile("s_waitcnt vmcnt(0) lgkmcnt(0)" ::: "memory");
  __builtin_amdgcn_s_barrier();
  __builtin_amdgcn_sched_barrier(0);
}

// ---------------- converts ----------------
__global__ __launch_bounds__(256) void k_cvt(const float* __restrict__ src,
                                             unsigned short* __restrict__ dst, int n4) {
  int i = blockIdx.x * blockDim.x + threadIdx.x;
  int stride = gridDim.x * blockDim.x;
  for (; i < n4; i += stride) {
    float4 v = ((const float4*)src)[i];
    ushort4 o;
    o.x = f2bf(v.x); o.y = f2bf(v.y); o.z = f2bf(v.z); o.w = f2bf(v.w);
    ((ushort4*)dst)[i] = o;
  }
}

// wk2 (512x128 f32) -> wk2t (128x512 bf16)
__global__ __launch_bounds__(256) void k_cvt_t(const float* __restrict__ src,
                                               unsigned short* __restrict__ dst) {
  int i = blockIdx.x * 256 + threadIdx.x;
  int o = i >> 7, d = i & 127;
  dst[d * 512 + o] = f2bf(src[i]);
}

// ---------------- fused attn1: wave-independent n-slices, LDS round-trips ----------------
// block = (b, head, branch); wave w owns keys n = tile_base + w*16 + [0,16).
// All fragment handoffs use the R2-verified LDS round-trip (write D as cvtpk b64
// pairs, read back [row=rn][kq*8] b128). K/V/P regions are wave-private -> the
// only barrier is the per-tile staging sync.
//
// LDS map (bytes):
//   0      .. 32768 : ctx double-buffer, 2 x [64][128] bf16
//   32768  .. 41984 : K_w,  per-wave [16][72] bf16 (K_w[key][d])
//   41984  .. 62464 : VT_w, per-wave [64][40] bf16 (VT_w[o][slot]; slots 4..7 of each octet = 0)
//   62464  .. 77824 : Q_lds [48][72] bf16 (prologue only), then P_w per-wave [48][40]
template <int BR>
__device__ __forceinline__ void attn_body(
    int sub,
    const unsigned short* __restrict__ st, const unsigned short* __restrict__ C,
    const unsigned short* __restrict__ wq, const unsigned short* __restrict__ wk1,
    const unsigned short* __restrict__ wv1, const int* __restrict__ maski,
    float* __restrict__ x, char* smem) {
  constexpr int AT = BR ? 3 : 1;
  constexpr int a0 = BR ? ND_ : 0;
  const int tid = threadIdx.x;
  const int w = tid >> 6, lane = tid & 63, rn = lane & 15, kq = lane >> 4;
  const int b = sub >> 3, h = sub & 7;

  unsigned short (*K_w)[72]  = (unsigned short (*)[72])(smem + 32768 + w * 2304);
  unsigned short (*VT_w)[40] = (unsigned short (*)[40])(smem + 41984 + w * 5120);
  unsigned short (*Q_lds)[72] = (unsigned short (*)[72])(smem + 62464);
  unsigned short (*P_w)[40]  = (unsigned short (*)[40])(smem + 62464 + w * 3840);

  // ---- stage tile 0 (swizzled global source, linear LDS)
#pragma unroll
  for (int i = 0; i < 4; ++i) {
    int r0 = i * 16 + w * 4, row = r0 + kq;
    gload16((const char*)C + (((size_t)b * N_ + row) << 8) + ((rn ^ (row & 7)) << 4),
            smem + (r0 << 8));
  }

  // ---- Q projection (R2-verified): wave w computes d-slice w for all agents
  {
    s16x8 qw[4];
#pragma unroll
    for (int kd = 0; kd < 4; ++kd)
      qw[kd] = *(const s16x8*)(wq + (size_t)(h * HD_ + w * 16 + rn) * DIN + kd * 32 + kq * 8);
#pragma unroll
    for (int at = 0; at < AT; ++at) {
      f32x4 acc = {0.f, 0.f, 0.f, 0.f};
#pragma unroll
      for (int kd = 0; kd < 4; ++kd) {
        s16x8 sf = *(const s16x8*)(st + (size_t)(b * A_ + a0 + at * 16 + rn) * DIN + kd * 32 + kq * 8);
        acc = mfma16(qw[kd], sf, acc);   // D[o-local][a]: lane holds Q[a=rn][o=w*16+kq*4+r]
      }
      uint2 pk; pk.x = cvtpk(acc[0], acc[1]); pk.y = cvtpk(acc[2], acc[3]);
      *(uint2*)&Q_lds[at * 16 + rn][w * 16 + kq * 4] = pk;
    }
  }

  // ---- persistent weight fragments (plain rows; verified pattern class)
  s16x8 kfrag[4][4], vfrag[4][4];
#pragma unroll
  for (int s = 0; s < 4; ++s) {
    const size_t orow = (size_t)(h * HD_ + s * 16 + rn) * DIN;
#pragma unroll
    for (int kd = 0; kd < 4; ++kd) {
      kfrag[s][kd] = *(const s16x8*)(wk1 + orow + kd * 32 + kq * 8);
      vfrag[s][kd] = *(const s16x8*)(wv1 + orow + kd * 32 + kq * 8);
    }
  }

  __syncthreads();   // Q_lds written by all waves

  // Q B-fragments to registers (R2-verified read pattern)
  s16x8 qf[AT][2];
#pragma unroll
  for (int at = 0; at < AT; ++at)
#pragma unroll
    for (int kd = 0; kd < 2; ++kd)
      qf[at][kd] = *(const s16x8*)&Q_lds[at * 16 + rn][kd * 32 + kq * 8];

  __syncthreads();   // all waves done reading Q_lds; P_w region may be written

  // zero-pad the dead slots (kq*8+4..7) of P_w and VT_w ONCE
  {
    uint2 z; z.x = 0u; z.y = 0u;
#pragma unroll
    for (int at = 0; at < AT; ++at)
      *(uint2*)&P_w[at * 16 + rn][kq * 8 + 4] = z;
#pragma unroll
    for (int s = 0; s < 4; ++s)
      *(uint2*)&VT_w[s * 16 + rn][kq * 8 + 4] = z;
  }

  f32x4 O[AT][4];
  float lpart[AT];
#pragma unroll
  for (int at = 0; at < AT; ++at) {
    lpart[at] = 0.f;
#pragma unroll
    for (int s = 0; s < 4; ++s) O[at][s] = {0.f, 0.f, 0.f, 0.f};
  }

  const size_t mbase = (size_t)(b * A_ + a0 + rn) * N_;

  for (int nt = 0; nt < NT_; ++nt) {
    __syncthreads();   // tile nt staged (sync drains vmcnt); prev-tile LDS reads done
    const int n0 = nt * 64;

    // mask loads for this tile
    int4 mv[AT];
    const int ngb = n0 + w * 16 + kq * 4;
    const int ngc = ngb > (N_ - 4) ? (N_ - 4) : ngb;
#pragma unroll
    for (int at = 0; at < AT; ++at)
      mv[at] = *(const int4*)(maski + mbase + (size_t)(at * 16) * N_ + ngc);

    // async prefetch tile nt+1 (rows clamped to N_-1: finite data always)
    if (nt + 1 < NT_) {
      char* dst = smem + ((nt + 1) & 1) * 16384;
#pragma unroll
      for (int i = 0; i < 4; ++i) {
        int r0 = i * 16 + w * 4, row = r0 + kq;
        int rg = n0 + 64 + row; rg = rg < N_ ? rg : (N_ - 1);
        gload16((const char*)C + (((size_t)b * N_ + rg) << 8) + ((rn ^ (row & 7)) << 4),
                dst + (r0 << 8));
      }
    }

    // ctx fragments for this wave's 16 keys (conflict-free swizzled b128)
    const unsigned short (*buf)[128] = (const unsigned short (*)[128])(smem + (nt & 1) * 16384);
    s16x8 cf[4];
#pragma unroll
    for (int kd = 0; kd < 4; ++kd)
      cf[kd] = *(const s16x8*)&buf[w * 16 + rn][(((kd << 2) | kq) ^ (rn & 7)) << 3];

    // ---- K projection: A=kfrag (o-rows), B=cf (key-cols)
    //      D[o-local][key]: lane holds K[key=rn][o=s*16+kq*4+r] -> K_w[key][d]
#pragma unroll
    for (int s = 0; s < 4; ++s) {
      f32x4 aK = {0.f, 0.f, 0.f, 0.f};
#pragma unroll
      for (int kd = 0; kd < 4; ++kd) aK = mfma16(kfrag[s][kd], cf[kd], aK);
      uint2 pk; pk.x = cvtpk(aK[0], aK[1]); pk.y = cvtpk(aK[2], aK[3]);
      *(uint2*)&K_w[rn][s * 16 + kq * 4] = pk;
    }

    // ---- V projection: A=cf (key-rows), B=vfrag (o-cols)
    //      D[key][o]: lane holds V[key=kq*4+r][o=s*16+rn] -> VT_w[o][slot kq*8+r]
#pragma unroll
    for (int s = 0; s < 4; ++s) {
      f32x4 aV = {0.f, 0.f, 0.f, 0.f};
#pragma unroll
      for (int kd = 0; kd < 4; ++kd) aV = mfma16(cf[kd], vfrag[s][kd], aV);
      uint2 pk; pk.x = cvtpk(aV[0], aV[1]); pk.y = cvtpk(aV[2], aV[3]);
      *(uint2*)&VT_w[s * 16 + rn][kq * 8] = pk;
    }

    // ---- QK^T: A = K_w rows (keys), B = qf (agents)
    s16x8 kf[2];
#pragma unroll
    for (int kd = 0; kd < 2; ++kd)
      kf[kd] = *(const s16x8*)&K_w[rn][kd * 32 + kq * 8];
#pragma unroll
    for (int at = 0; at < AT; ++at) {
      f32x4 acc = {0.f, 0.f, 0.f, 0.f};
      acc = mfma16(kf[0], qf[at][0], acc);
      acc = mfma16(kf[1], qf[at][1], acc);
      // lane reg r = S[key = ngb + r][agent = a0 + at*16 + rn]
      float p0 = ((ngb + 0 < N_) && (mv[at].x == 0)) ? __expf(acc[0] * 0.125f - 8.0f) : 0.f;
      float p1 = ((ngb + 1 < N_) && (mv[at].y == 0)) ? __expf(acc[1] * 0.125f - 8.0f) : 0.f;
      float p2 = ((ngb + 2 < N_) && (mv[at].z == 0)) ? __expf(acc[2] * 0.125f - 8.0f) : 0.f;
      float p3 = ((ngb + 3 < N_) && (mv[at].w == 0)) ? __expf(acc[3] * 0.125f - 8.0f) : 0.f;
      lpart[at] += (p0 + p1) + (p2 + p3);
      uint2 pk; pk.x = cvtpk(p0, p1); pk.y = cvtpk(p2, p3);
      *(uint2*)&P_w[at * 16 + rn][kq * 8] = pk;   // slots kq*8+0..3 = keys kq*4+0..3
    }

    // ---- PV: A = P_w rows (agents), B = VT_w (o-cols), zero-padded K=32
    s16x8 vtf[4];
#pragma unroll
    for (int s = 0; s < 4; ++s)
      vtf[s] = *(const s16x8*)&VT_w[s * 16 + rn][kq * 8];
#pragma unroll
    for (int at = 0; at < AT; ++at) {
      s16x8 pa = *(const s16x8*)&P_w[at * 16 + rn][kq * 8];
#pragma unroll
      for (int s = 0; s < 4; ++s)
        O[at][s] = mfma16(pa, vtf[s], O[at][s]);   // D: O[a=at*16+kq*4+r][o=s*16+rn]
    }
  }

  // ---- epilogue: cross-wave reduce of l and O, then write x
  __syncthreads();
  float* redl = (float*)smem;            // [4][48]
  float* lsum = (float*)(smem + 1024);   // [48]
  float* redO = (float*)(smem + 2048);   // [4][6][256]
#pragma unroll
  for (int at = 0; at < AT; ++at) {
    float lp = lpart[at];
    lp += __shfl_xor(lp, 16);
    lp += __shfl_xor(lp, 32);
    if (kq == 0) redl[w * 48 + at * 16 + rn] = lp;
  }
  __syncthreads();
  if (tid < 16 * AT) lsum[tid] = redl[tid] + redl[48 + tid] + redl[96 + tid] + redl[144 + tid];

#pragma unroll
  for (int p = 0; p < 2; ++p) {
    __syncthreads();   // p=0: lsum ready; p=1: phase-0 reads done
#pragma unroll
    for (int at = 0; at < AT; ++at)
#pragma unroll
      for (int q = 0; q < 2; ++q)
        *(f32x4*)&redO[(w * 6 + at * 2 + q) * 256 + lane * 4] = O[at][p * 2 + q];
    __syncthreads();
    for (int t = w; t < 2 * AT; t += 4) {
      int at = t >> 1;
      int sp = p * 2 + (t & 1);
      f32x4 v  = *(const f32x4*)&redO[(0 * 6 + t) * 256 + lane * 4];
      f32x4 v1 = *(const f32x4*)&redO[(1 * 6 + t) * 256 + lane * 4];
      f32x4 v2 = *(const f32x4*)&redO[(2 * 6 + t) * 256 + lane * 4];
      f32x4 v3 = *(const f32x4*)&redO[(3 * 6 + t) * 256 + lane * 4];
      v = (v + v1) + (v2 + v3);
#pragma unroll
      for (int r = 0; r < 4; ++r) {
        int a_idx = at * 16 + kq * 4 + r;
        float ls = lsum[at * 16 + kq * 4 + r];
        int d = sp * 16 + rn;
        int row = BR ? (ND_ + h * 6 + (a_idx >> 3)) : (h * 2 + (a_idx >> 3));
        x[((size_t)b * A_ + row) * HID + (a_idx & 7) * HD_ + d] = v[r] / ls;
      }
    }
  }
}

__global__ __launch_bounds__(256) void k_attn1(const unsigned short* __restrict__ st,
                                               const unsigned short* __restrict__ ctx,
                                               const unsigned short* __restrict__ ctxd,
                                               const unsigned short* __restrict__ wq,
                                               const unsigned short* __restrict__ wk1,
                                               const unsigned short* __restrict__ wv1,
                                               const int* __restrict__ maski,
                                               float* __restrict__ x) {
  __shared__ __align__(16) char smem[77824];
  const int bid = blockIdx.x;
  const int sub = bid >> 1;
  if (bid & 1)
    attn_body<1>(sub, st, ctx, wq, wk1, wv1, maski, x, smem);
  else
    attn_body<0>(sub, st, ctxd, wq, wk1, wv1, maski, x, smem);
}

// ---------------- fused fc + y2: y2 = norm2 * ((x @ wfc^T) @ wk2) ----------------
__global__ __launch_bounds__(256) void k_fc2(const float* __restrict__ x,
                                             const unsigned short* __restrict__ wfc,
                                             const unsigned short* __restrict__ wk2t,
                                             unsigned short* __restrict__ y2b) {
  __shared__ unsigned short x2_lds[16][520];
  const int tid = threadIdx.x;
  const int w = tid >> 6;
  const int lane = tid & 63;
  const int rn = lane & 15, kq = lane >> 4;
  const size_t rowbase = (size_t)blockIdx.x * 16;
  const float norm2 = 0.04419417382415922f;   // 1/sqrt(512)

  f32x4 acc[8];
#pragma unroll
  for (int ot = 0; ot < 8; ++ot) acc[ot] = {0.f, 0.f, 0.f, 0.f};

  for (int k = 0; k < 16; ++k) {
    const float* ap = x + (rowbase + rn) * HID + k * 32 + kq * 8;
    float4 a1 = *(const float4*)ap;
    float4 a2 = *(const float4*)(ap + 4);
    s16x8 af;
    af[0] = (short)f2bf(a1.x); af[1] = (short)f2bf(a1.y);
    af[2] = (short)f2bf(a1.z); af[3] = (short)f2bf(a1.w);
    af[4] = (short)f2bf(a2.x); af[5] = (short)f2bf(a2.y);
    af[6] = (short)f2bf(a2.z); af[7] = (short)f2bf(a2.w);
#pragma unroll
    for (int ot = 0; ot < 8; ++ot) {
      s16x8 bf = *(const s16x8*)(wfc + (size_t)(w * 128 + ot * 16 + rn) * HID + k * 32 + kq * 8);
      acc[ot] = mfma16(af, bf, acc[ot]);
    }
  }
#pragma unroll
  for (int ot = 0; ot < 8; ++ot)
#pragma unroll
    for (int r = 0; r < 4; ++r)
      x2_lds[kq * 4 + r][w * 128 + ot * 16 + rn] = f2bf(acc[ot][r]);
  __syncthreads();

#pragma unroll
  for (int j = 0; j < 2; ++j) {
    const int d0 = w * 32 + j * 16;
    f32x4 acc2 = {0.f, 0.f, 0.f, 0.f};
    for (int kk = 0; kk < 16; ++kk) {
      s16x8 af2 = *(const s16x8*)&x2_lds[rn][kk * 32 + kq * 8];
      s16x8 bf2 = *(const s16x8*)(wk2t + (size_t)(d0 + rn) * HID + kk * 32 + kq * 8);
      acc2 = mfma16(af2, bf2, acc2);
    }
#pragma unroll
    for (int r = 0; r < 4; ++r)
      y2b[(rowbase + kq * 4 + r) * DIN + d0 + rn] = f2bf(acc2[r] * norm2);
  }
}

// ---------------- fused logits + softmax ----------------
__global__ __launch_bounds__(256) void k_logits_sm(const unsigned short* __restrict__ ctx,
                                                   const unsigned short* __restrict__ ctxd,
                                                   const unsigned short* __restrict__ y2b,
                                                   const int* __restrict__ maski,
                                                   const int* __restrict__ Tptr,
                                                   float* __restrict__ out) {
  __shared__ unsigned short ctx_lds[3][64][128];
  __shared__ unsigned short p_lds[16][2048];
  __shared__ float red_l[4][16];

  const int tid = threadIdx.x;
  const int w = tid >> 6, lane = tid & 63, rn = lane & 15, kq = lane >> 4;
  const int atile = blockIdx.x;           // 0..3
  const int b = blockIdx.y;
  const int a0 = atile * 16;
  const unsigned short* __restrict__ C = atile ? ctx : ctxd;
  const float Tinv = 1.0f / (float)Tptr[0];
  const int srow = lane >> 4, scol = lane & 15;
  const size_t bN = (size_t)b * N_;
  const size_t mrow = (size_t)(b * A_ + a0 + rn) * N_;

  s16x8 yf[4];
#pragma unroll
  for (int kd = 0; kd < 4; ++kd)
    yf[kd] = *(const s16x8*)(y2b + (size_t)(b * A_ + a0 + rn) * DIN + kd * 32 + kq * 8);

  int4 mcur = *(const int4*)(maski + mrow + w * 16 + kq * 4);
#pragma unroll
  for (int i = 0; i < 4; ++i) {
    int r0 = i * 16 + w * 4;
    int row = r0 + srow;
    gload16((const char*)C + ((bN + row) << 8) + ((scol ^ (row & 7)) << 4),
            (char*)&ctx_lds[0][0][0] + (r0 << 8));
  }
#pragma unroll
  for (int i = 0; i < 4; ++i) {
    int r0 = i * 16 + w * 4;
    int row = r0 + srow;
    gload16((const char*)C + ((bN + 64 + row) << 8) + ((scol ^ (row & 7)) << 4),
            (char*)&ctx_lds[1][0][0] + (r0 << 8));
  }

  float lpart = 0.f;
  for (int nt = 0; nt < NT_; ++nt) {
    const int n0 = nt * 64;
    if (nt == 0) { asm volatile("s_waitcnt vmcnt(4)" ::: "memory"); }
    else         { asm volatile("s_waitcnt vmcnt(5)" ::: "memory"); }
    __builtin_amdgcn_s_barrier();
    __builtin_amdgcn_sched_barrier(0);

    int4 mnext;
    {
      int nb1 = (nt + 1 < NT_ ? nt + 1 : 0) * 64 + w * 16 + kq * 4;
      int ngc = nb1 > (N_ - 4) ? (N_ - 4) : nb1;
      mnext = *(const int4*)(maski + mrow + ngc);
    }
    {
      int t2 = nt + 2 < NT_ ? nt + 2 : 0;
      char* dstb = (char*)&ctx_lds[(nt + 2) % 3][0][0];
#pragma unroll
      for (int i = 0; i < 4; ++i) {
        int r0 = i * 16 + w * 4;
        int row = r0 + srow;
        gload16((const char*)C + ((bN + t2 * 64 + row) << 8) + ((scol ^ (row & 7)) << 4),
                dstb + (r0 << 8));
      }
    }

    const unsigned short (*buf)[128] = ctx_lds[nt % 3];
    f32x4 acc = {0.f, 0.f, 0.f, 0.f};
#pragma unroll
    for (int kd = 0; kd < 4; ++kd) {
      s16x8 cf = *(const s16x8*)&buf[w * 16 + rn][(((kd << 2) | kq) ^ (rn & 7)) << 3];
      acc = mfma16(cf, yf[kd], acc);
    }
    const int nbase = n0 + w * 16 + kq * 4;
    float pv0 = ((nbase + 0 < N_) && (mcur.x == 0)) ? __expf(acc[0] * Tinv - 8.0f) : 0.f;
    float pv1 = ((nbase + 1 < N_) && (mcur.y == 0)) ? __expf(acc[1] * Tinv - 8.0f) : 0.f;
    float pv2 = ((nbase + 2 < N_) && (mcur.z == 0)) ? __expf(acc[2] * Tinv - 8.0f) : 0.f;
    float pv3 = ((nbase + 3 < N_) && (mcur.w == 0)) ? __expf(acc[3] * Tinv - 8.0f) : 0.f;
    lpart += (pv0 + pv1) + (pv2 + pv3);
    uint2 pk; pk.x = cvtpk(pv0, pv1); pk.y = cvtpk(pv2, pv3);
    int bo = (rn << 12) + (nbase << 1);
    *(uint2*)((char*)p_lds + (bo ^ ((rn & 7) << 4))) = pk;
    mcur = mnext;
  }

  float lp = lpart;
  lp += __shfl_xor(lp, 16);
  lp += __shfl_xor(lp, 32);
  if (kq == 0) red_l[w][rn] = lp;
  barrier_full();

  const size_t outbase = ((size_t)b * A_ + a0) * (size_t)N_;
  for (int row = 0; row < 16; ++row) {
    float l = (red_l[0][row] + red_l[1][row]) + (red_l[2][row] + red_l[3][row]);
    float inv = 1.0f / l;
    if (tid < 250) {
      const char* srcp = (const char*)p_lds + (row << 12) + ((tid ^ (row & 7)) << 4);
      uint2 pk = *(const uint2*)srcp;
      float4 o0, o1;
      o0.x = bf2f(pk.x & 0xFFFFu) * inv;
      o0.y = bf2f(pk.x >> 16) * inv;
      o0.z = bf2f(pk.y & 0xFFFFu) * inv;
      o0.w = bf2f(pk.y >> 16) * inv;
      uint2 pk2 = *(const uint2*)(srcp + 8);
      o1.x = bf2f(pk2.x & 0xFFFFu) * inv;
      o1.y = bf2f(pk2.x >> 16) * inv;
      o1.z = bf2f(pk2.y & 0xFFFFu) * inv;
      o1.w = bf2f(pk2.y >> 16) * inv;
      float* op = out + outbase + (size_t)row * N_ + tid * 8;
      *(float4*)op = o0;
      *(float4*)(op + 4) = o1;
    }
  }
}

// ---------------- launch ----------------
extern "C" void kernel_launch(void* const* d_in, const int* in_sizes, int n_in,
                              void* d_out, int out_size, void* d_ws, size_t ws_size,
                              hipStream_t stream) {
  const float* state_t   = (const float*)d_in[0];
  const float* context   = (const float*)d_in[1];
  const float* context_d = (const float*)d_in[2];
  const float* w_q  = (const float*)d_in[3];
  const float* w_k1 = (const float*)d_in[4];
  const float* w_v1 = (const float*)d_in[5];
  const float* w_fc = (const float*)d_in[6];
  const float* w_k2 = (const float*)d_in[7];
  const int* maski  = (const int*)d_in[9];
  const int* Tptr   = (const int*)d_in[10];
  float* out = (float*)d_out;

  char* ws = (char*)d_ws;
  unsigned short* ctxb  = (unsigned short*)ws; ws += (size_t)B_ * N_ * DIN * 2;
  unsigned short* ctxdb = (unsigned short*)ws; ws += (size_t)B_ * N_ * DIN * 2;
  unsigned short* stb   = (unsigned short*)ws; ws += (size_t)B_ * A_ * DIN * 2;
  unsigned short* wqb   = (unsigned short*)ws; ws += (size_t)HID * DIN * 2;
  unsigned short* wk1b  = (unsigned short*)ws; ws += (size_t)HID * DIN * 2;
  unsigned short* wv1b  = (unsigned short*)ws; ws += (size_t)HID * DIN * 2;
  unsigned short* wk2t  = (unsigned short*)ws; ws += (size_t)HID * DIN * 2;
  unsigned short* wfcb  = (unsigned short*)ws; ws += (size_t)HID * HID * 2;
  float*          x     = (float*)ws;          ws += (size_t)B_ * A_ * HID * 4;
  unsigned short* y2b   = (unsigned short*)ws; ws += (size_t)B_ * A_ * DIN * 2;

  k_cvt<<<2048, 256, 0, stream>>>(context,   ctxb,  B_ * N_ * DIN / 4);
  k_cvt<<<2048, 256, 0, stream>>>(context_d, ctxdb, B_ * N_ * DIN / 4);
  k_cvt<<<256,  256, 0, stream>>>(state_t,   stb,   B_ * A_ * DIN / 4);
  k_cvt<<<64,   256, 0, stream>>>(w_q,  wqb,  HID * DIN / 4);
  k_cvt<<<64,   256, 0, stream>>>(w_k1, wk1b, HID * DIN / 4);
  k_cvt<<<64,   256, 0, stream>>>(w_v1, wv1b, HID * DIN / 4);
  k_cvt_t<<<256, 256, 0, stream>>>(w_k2, wk2t);
  k_cvt<<<256,  256, 0, stream>>>(w_fc, wfcb, HID * HID / 4);

  k_attn1<<<2048, 256, 0, stream>>>(stb, ctxb, ctxdb, wqb, wk1b, wv1b, maski, x);

  k_fc2<<<(B_ * A_) / 16, 256, 0, stream>>>(x, wfcb, wk2t, y2b);

  dim3 gl(4, B_);
  k_logits_sm<<<gl, 256, 0, stream>>>(ctxb, ctxdb, y2b, maski, Tptr, out);
}